// Round 5
// baseline (847.496 us; speedup 1.0000x reference)
//
#include <hip/hip_runtime.h>
#include <hip/hip_bf16.h>
#include <math.h>

#define N_NODES 100000
#define N_EDGES 1600000
#define D_IN    256
#define D_HID   64
#define N_CLASS 40

#define SCAN_CHUNK 256
#define SCAN_NB    ((N_NODES + SCAN_CHUNK - 1) / SCAN_CHUNK)   // 391
#define SLOT_MAX   48   // Binomial(1.6M,1e-5): mean 16, P(deg>48) ~ 1e-10

// ---------------------------------------------------------------------------
// prep: W12t[c][k] = sum_j W1[k][j]*W2[j][c]  (TRANSPOSED, 40x256),
//       c1[c] = sum_j b1[j]*W2[j][c]
// ---------------------------------------------------------------------------
__global__ __launch_bounds__(256) void prep_kernel(
    const float* __restrict__ W1, const float* __restrict__ W2,
    const float* __restrict__ b1, float* __restrict__ W12t, float* __restrict__ c1)
{
    int idx = blockIdx.x * 256 + threadIdx.x;
    if (idx < D_IN * N_CLASS) {
        int k = idx / N_CLASS;
        int c = idx - k * N_CLASS;
        float s = 0.f;
#pragma unroll
        for (int j = 0; j < D_HID; ++j)
            s = fmaf(W1[k * D_HID + j], W2[j * N_CLASS + c], s);
        W12t[c * D_IN + k] = s;
    }
    if (blockIdx.x == 0 && threadIdx.x < N_CLASS) {
        int c = threadIdx.x;
        float s = 0.f;
#pragma unroll
        for (int j = 0; j < D_HID; ++j)
            s = fmaf(b1[j], W2[j * N_CLASS + c], s);
        c1[c] = s;
    }
}

// ---------------------------------------------------------------------------
// gemm_t v2: T[N,40] = X[N,256] @ W12t'[256,40]
// 32 rows/block, 3125 blocks. X tile staged in LDS with fully-coalesced
// wave loads (one 1KB row per wave instruction), stride 260 (pad 4) keeps
// float4 alignment and conflict-free reads. Thread = 1 row x 5 cols; weights
// read k-contiguous from W12t (40KB, L1-resident, wave-broadcast).
// ---------------------------------------------------------------------------
__global__ __launch_bounds__(256) void gemm_t_kernel(
    const float* __restrict__ x, const float* __restrict__ W12t,
    float* __restrict__ T)
{
    __shared__ float xs[32 * 260];   // 33.3 KB
    const int tid = threadIdx.x;
    const int row0 = blockIdx.x * 32;

    // coalesced stage: 32 rows x 64 float4; wave i covers one full row chunk
    for (int i = tid; i < 32 * 64; i += 256) {
        int r  = i >> 6;
        int c4 = i & 63;
        float4 v = ((const float4*)x)[(size_t)(row0 + r) * 64 + c4];
        *((float4*)&xs[r * 260 + c4 * 4]) = v;
    }
    __syncthreads();

    const int row = tid >> 3;        // 0..31
    const int cg  = tid & 7;         // 8 col-groups
    const int c0  = cg * 5;          // 5 cols each

    float acc[5];
#pragma unroll
    for (int j = 0; j < 5; ++j) acc[j] = 0.f;

    const float* xr = &xs[row * 260];
#pragma unroll 2
    for (int k4 = 0; k4 < D_IN / 4; ++k4) {
        float4 xv = *(const float4*)&xr[k4 * 4];
#pragma unroll
        for (int j = 0; j < 5; ++j) {
            float4 w = ((const float4*)W12t)[(c0 + j) * (D_IN / 4) + k4];
            acc[j] = fmaf(xv.x, w.x, fmaf(xv.y, w.y, fmaf(xv.z, w.z, fmaf(xv.w, w.w, acc[j]))));
        }
    }

    size_t ob = (size_t)(row0 + row) * N_CLASS + c0;
#pragma unroll
    for (int j = 0; j < 5; ++j) T[ob + j] = acc[j];
}

// ---------------------------------------------------------------------------
// hist: cnt[dst]++ only (CSR fallback path)
// ---------------------------------------------------------------------------
__global__ __launch_bounds__(256) void hist_kernel(
    const int* __restrict__ edst, int* __restrict__ cnt)
{
    int e = blockIdx.x * 256 + threadIdx.x;
    if (e >= N_EDGES) return;
    atomicAdd(&cnt[edst[e]], 1);
}

// ---------------------------------------------------------------------------
// 3-phase parallel exclusive scan of cnt -> row_ptr (CSR fallback path)
// ---------------------------------------------------------------------------
__global__ __launch_bounds__(256) void scan_partial_kernel(
    const int* __restrict__ cnt, int* __restrict__ bsum)
{
    __shared__ int red[256];
    int t = threadIdx.x;
    int idx = blockIdx.x * SCAN_CHUNK + t;
    int v = (idx < N_NODES) ? cnt[idx] : 0;
    red[t] = v;
    __syncthreads();
#pragma unroll
    for (int off = 128; off > 0; off >>= 1) {
        if (t < off) red[t] += red[t + off];
        __syncthreads();
    }
    if (t == 0) bsum[blockIdx.x] = red[0];
}

__global__ __launch_bounds__(512) void scan_block_kernel(
    const int* __restrict__ bsum, int* __restrict__ boff)
{
    __shared__ int s[512];
    int t = threadIdx.x;
    int v = (t < SCAN_NB) ? bsum[t] : 0;
    s[t] = v;
    __syncthreads();
#pragma unroll
    for (int off = 1; off < 512; off <<= 1) {
        int u = (t >= off) ? s[t - off] : 0;
        __syncthreads();
        s[t] += u;
        __syncthreads();
    }
    if (t < SCAN_NB) boff[t] = s[t] - v;   // exclusive
}

__global__ __launch_bounds__(256) void scan_final_kernel(
    const int* __restrict__ cnt, const int* __restrict__ boff,
    int* __restrict__ row_ptr)
{
    __shared__ int s[256];
    int t = threadIdx.x;
    int idx = blockIdx.x * SCAN_CHUNK + t;
    int v = (idx < N_NODES) ? cnt[idx] : 0;
    s[t] = v;
    __syncthreads();
#pragma unroll
    for (int off = 1; off < 256; off <<= 1) {
        int u = (t >= off) ? s[t - off] : 0;
        __syncthreads();
        s[t] += u;
        __syncthreads();
    }
    if (idx < N_NODES) row_ptr[idx] = boff[blockIdx.x] + s[t] - v;
}

// ---------------------------------------------------------------------------
// fill (CSR fallback): pos = row_ptr[d]++; afterwards row_ptr[d] = end of row d
// ---------------------------------------------------------------------------
__global__ __launch_bounds__(256) void fill_kernel(
    const int* __restrict__ esrc, const int* __restrict__ edst,
    const float* __restrict__ ew, int* __restrict__ row_ptr,
    int2* __restrict__ edges_s)
{
    int e = blockIdx.x * 256 + threadIdx.x;
    if (e >= N_EDGES) return;
    int d = edst[e];
    int pos = atomicAdd(&row_ptr[d], 1);
    edges_s[pos] = make_int2(esrc[e], __float_as_int(ew[e]));
}

// ---------------------------------------------------------------------------
// fill (slots): one pass, no hist/scan. slot = cnt[d]++; bucket at d*SLOT_MAX.
// ---------------------------------------------------------------------------
__global__ __launch_bounds__(256) void fill_slots_kernel(
    const int* __restrict__ esrc, const int* __restrict__ edst,
    const float* __restrict__ ew, int* __restrict__ cnt,
    int2* __restrict__ slots)
{
    int e = blockIdx.x * 256 + threadIdx.x;
    if (e >= N_EDGES) return;
    int d = edst[e];
    int slot = atomicAdd(&cnt[d], 1);
    if (slot < SLOT_MAX)
        slots[(size_t)d * SLOT_MAX + slot] = make_int2(esrc[e], __float_as_int(ew[e]));
}

// ---------------------------------------------------------------------------
// agg: Tout[d,:] = sum_e w_e * Tin[src_e,:]. 10 lanes x float4 per node,
// 25 nodes / 256-block. Also writes deg_w[d] = sum_e w_e (sub==0 lane).
// ---------------------------------------------------------------------------
template<bool SLOTS>
__global__ __launch_bounds__(256) void agg_kernel(
    const int2* __restrict__ edges_s, const int* __restrict__ meta,
    const float* __restrict__ Tin, float* __restrict__ Tout,
    float* __restrict__ deg_w)
{
    const int t = threadIdx.x;
    if (t >= 250) return;
    const int node = blockIdx.x * 25 + t / 10;
    if (node >= N_NODES) return;
    const int sub = t % 10;

    int beg, end;
    if (SLOTS) {
        beg = node * SLOT_MAX;
        int c = meta[node];
        end = beg + (c > SLOT_MAX ? SLOT_MAX : c);
    } else {
        beg = node ? meta[node - 1] : 0;
        end = meta[node];
    }

    const float4* Tin4 = (const float4*)Tin;
    float4 acc = make_float4(0.f, 0.f, 0.f, 0.f);
    float wsum = 0.f;

    int e = beg;
    for (; e + 1 < end; e += 2) {
        int2 r0 = edges_s[e];
        int2 r1 = edges_s[e + 1];
        float w0 = __int_as_float(r0.y);
        float w1 = __int_as_float(r1.y);
        float4 v0 = Tin4[(size_t)r0.x * 10 + sub];
        float4 v1 = Tin4[(size_t)r1.x * 10 + sub];
        acc.x = fmaf(w0, v0.x, acc.x); acc.y = fmaf(w0, v0.y, acc.y);
        acc.z = fmaf(w0, v0.z, acc.z); acc.w = fmaf(w0, v0.w, acc.w);
        acc.x = fmaf(w1, v1.x, acc.x); acc.y = fmaf(w1, v1.y, acc.y);
        acc.z = fmaf(w1, v1.z, acc.z); acc.w = fmaf(w1, v1.w, acc.w);
        wsum += w0 + w1;
    }
    if (e < end) {
        int2 r0 = edges_s[e];
        float w0 = __int_as_float(r0.y);
        float4 v0 = Tin4[(size_t)r0.x * 10 + sub];
        acc.x = fmaf(w0, v0.x, acc.x); acc.y = fmaf(w0, v0.y, acc.y);
        acc.z = fmaf(w0, v0.z, acc.z); acc.w = fmaf(w0, v0.w, acc.w);
        wsum += w0;
    }

    ((float4*)Tout)[(size_t)node * 10 + sub] = acc;
    if (sub == 0) deg_w[node] = wsum;   // same A both layers -> idempotent
}

// ---------------------------------------------------------------------------
// log_softmax over rows of (Y2 + deg_w*c1 + b2). One wave per row.
// ---------------------------------------------------------------------------
__global__ __launch_bounds__(256) void softmax_kernel(
    const float* __restrict__ Y2, const float* __restrict__ deg_w,
    const float* __restrict__ c1, const float* __restrict__ b2,
    float* __restrict__ out)
{
    int row = blockIdx.x * 4 + (threadIdx.x >> 6);
    int lane = threadIdx.x & 63;
    if (row >= N_NODES) return;

    float z = -INFINITY;
    if (lane < N_CLASS)
        z = Y2[(size_t)row * N_CLASS + lane] + deg_w[row] * c1[lane] + b2[lane];

    float m = z;
#pragma unroll
    for (int o = 32; o > 0; o >>= 1) m = fmaxf(m, __shfl_xor(m, o, 64));

    float ex = (lane < N_CLASS) ? expf(z - m) : 0.f;
    float ssum = ex;
#pragma unroll
    for (int o = 32; o > 0; o >>= 1) ssum += __shfl_xor(ssum, o, 64);

    if (lane < N_CLASS) out[(size_t)row * N_CLASS + lane] = z - m - logf(ssum);
}

// ---------------------------------------------------------------------------
extern "C" void kernel_launch(void* const* d_in, const int* in_sizes, int n_in,
                              void* d_out, int out_size, void* d_ws, size_t ws_size,
                              hipStream_t stream)
{
    const float* x    = (const float*)d_in[0];
    const int*   esrc = (const int*)  d_in[1];
    const int*   edst = (const int*)  d_in[2];
    const float* ew   = (const float*)d_in[3];
    const float* W1   = (const float*)d_in[4];
    const float* b1   = (const float*)d_in[5];
    const float* W2   = (const float*)d_in[6];
    const float* b2   = (const float*)d_in[7];
    float* out = (float*)d_out;

    char* ws = (char*)d_ws;
    const size_t SLOTS_BYTES = (size_t)N_NODES * SLOT_MAX * 8;     // 38.4 MB
    const size_t NEED_SLOTS  = SLOTS_BYTES + 32000000 + 1000000;   // ~71.4 MB
    const bool use_slots = (ws_size >= NEED_SLOTS);

    if (use_slots) {
        int2*  slots = (int2*) (ws);
        float* T     = (float*)(ws + SLOTS_BYTES);                  // 16 MB
        float* Y1    = (float*)(ws + SLOTS_BYTES + 16000000);       // 16 MB
        int*   cnt   = (int*)  (ws + SLOTS_BYTES + 32000000);       // 400 KB
        float* deg_w = (float*)(ws + SLOTS_BYTES + 32400000);       // 400 KB
        float* W12t  = (float*)(ws + SLOTS_BYTES + 32800000);       // 40 KB
        float* c1    = (float*)(ws + SLOTS_BYTES + 32841984);
        float* Y2    = T;

        hipMemsetAsync(cnt, 0, 400000, stream);
        prep_kernel<<<(D_IN * N_CLASS + 255) / 256, 256, 0, stream>>>(W1, W2, b1, W12t, c1);
        gemm_t_kernel<<<N_NODES / 32, 256, 0, stream>>>(x, W12t, T);
        fill_slots_kernel<<<(N_EDGES + 255) / 256, 256, 0, stream>>>(esrc, edst, ew, cnt, slots);
        agg_kernel<true><<<(N_NODES + 24) / 25, 256, 0, stream>>>(slots, cnt, T, Y1, deg_w);
        agg_kernel<true><<<(N_NODES + 24) / 25, 256, 0, stream>>>(slots, cnt, Y1, Y2, deg_w);
        softmax_kernel<<<(N_NODES + 3) / 4, 256, 0, stream>>>(Y2, deg_w, c1, b2, out);
    } else {
        float* T       = (float*)(ws);                         // 16 MB (also Y2)
        float* Y1      = (float*)(ws + 16000000);              // 16 MB
        int2*  edges_s = (int2*) (ws + 32000000);              // 12.8 MB
        int*   row_ptr = (int*)  (ws + 44800000);              // 400 KB
        int*   cnt     = (int*)  (ws + 45200016);              // 400 KB
        float* deg_w   = (float*)(ws + 45600016);              // 400 KB
        float* W12t    = (float*)(ws + 46000016);              // 40 KB
        float* c1      = (float*)(ws + 46040976);
        int*   bsum    = (int*)  (ws + 46041200);
        int*   boff    = (int*)  (ws + 46042800);
        float* Y2      = T;

        hipMemsetAsync(cnt, 0, 400000, stream);
        prep_kernel<<<(D_IN * N_CLASS + 255) / 256, 256, 0, stream>>>(W1, W2, b1, W12t, c1);
        gemm_t_kernel<<<N_NODES / 32, 256, 0, stream>>>(x, W12t, T);
        hist_kernel<<<(N_EDGES + 255) / 256, 256, 0, stream>>>(edst, cnt);
        scan_partial_kernel<<<SCAN_NB, 256, 0, stream>>>(cnt, bsum);
        scan_block_kernel<<<1, 512, 0, stream>>>(bsum, boff);
        scan_final_kernel<<<SCAN_NB, 256, 0, stream>>>(cnt, boff, row_ptr);
        fill_kernel<<<(N_EDGES + 255) / 256, 256, 0, stream>>>(esrc, edst, ew, row_ptr, edges_s);
        agg_kernel<false><<<(N_NODES + 24) / 25, 256, 0, stream>>>(edges_s, row_ptr, T, Y1, deg_w);
        agg_kernel<false><<<(N_NODES + 24) / 25, 256, 0, stream>>>(edges_s, row_ptr, Y1, Y2, deg_w);
        softmax_kernel<<<(N_NODES + 3) / 4, 256, 0, stream>>>(Y2, deg_w, c1, b2, out);
    }
}

// Round 6
// 454.727 us; speedup vs baseline: 1.8637x; 1.8637x over previous
//
#include <hip/hip_runtime.h>
#include <hip/hip_bf16.h>
#include <math.h>

#define N_NODES 100000
#define N_EDGES 1600000
#define D_IN    256
#define D_HID   64
#define N_CLASS 40

#define SCAN_CHUNK 256
#define SCAN_NB    ((N_NODES + SCAN_CHUNK - 1) / SCAN_CHUNK)   // 391
#define SLOT_MAX   48   // Binomial(1.6M,1e-5): mean 16, P(deg>48) ~ 1e-10

// ---------------------------------------------------------------------------
// prep: W12t[c][k] = sum_j W1[k][j]*W2[j][c]  (TRANSPOSED, 40x256),
//       c1[c] = sum_j b1[j]*W2[j][c]
// ---------------------------------------------------------------------------
__global__ __launch_bounds__(256) void prep_kernel(
    const float* __restrict__ W1, const float* __restrict__ W2,
    const float* __restrict__ b1, float* __restrict__ W12t, float* __restrict__ c1)
{
    int idx = blockIdx.x * 256 + threadIdx.x;
    if (idx < D_IN * N_CLASS) {
        int k = idx / N_CLASS;
        int c = idx - k * N_CLASS;
        float s = 0.f;
#pragma unroll
        for (int j = 0; j < D_HID; ++j)
            s = fmaf(W1[k * D_HID + j], W2[j * N_CLASS + c], s);
        W12t[c * D_IN + k] = s;
    }
    if (blockIdx.x == 0 && threadIdx.x < N_CLASS) {
        int c = threadIdx.x;
        float s = 0.f;
#pragma unroll
        for (int j = 0; j < D_HID; ++j)
            s = fmaf(b1[j], W2[j * N_CLASS + c], s);
        c1[c] = s;
    }
}

// ---------------------------------------------------------------------------
// gemm_t v3: T[N,40] = X[N,256] @ W12t'[256,40]
// Both operands in LDS (v2's global-weight path missed L1: 40KB > 32KB).
// 256 rows x 40 cols per block; thread = 4 rows x 10 cols (VALU-bound:
// 160 FMA vs 14 ds_read_b128 per k4). X staged per 32-k block with XOR
// swizzle c4' = c4 ^ ((row>>2)&7): read = 16 addrs over 8 bank-groups
// (2-way, free); weights wt[40][260]: 4 cg addrs in groups {0,8,16,24},
// broadcast to 16 lanes, conflict-free. LDS 74.4KB -> 2 blocks/CU.
// ---------------------------------------------------------------------------
__global__ __launch_bounds__(256) void gemm_t_kernel(
    const float* __restrict__ x, const float* __restrict__ W12t,
    float* __restrict__ T)
{
    __shared__ float xs[256 * 32];      // 32 KB, float4-swizzled
    __shared__ float wt[N_CLASS * 260]; // 41.6 KB, [c][k] stride 260
    const int tid = threadIdx.x;
    const int row0 = blockIdx.x * 256;

    // stage full W12t once: lane-consecutive k -> conflict-free LDS writes,
    // coalesced global reads
    for (int i = tid; i < N_CLASS * D_IN; i += 256) {
        int c = i >> 8;
        int k = i & 255;
        wt[c * 260 + k] = W12t[i];
    }

    const int rg = tid >> 2;       // 0..63  (4 rows each)
    const int cg = tid & 3;        // 0..3   (10 cols each)
    const int c0 = cg * 10;

    float acc[4][10];
#pragma unroll
    for (int r = 0; r < 4; ++r)
#pragma unroll
        for (int j = 0; j < 10; ++j) acc[r][j] = 0.f;

    const float4* x4 = (const float4*)x;
    float4* xs4 = (float4*)xs;
    const float4* wt4 = (const float4*)wt;

    for (int kb = 0; kb < 8; ++kb) {
        __syncthreads();   // protect xs from previous iteration's readers
        // stage 256 rows x 8 float4 (k = kb*32..+31), swizzled
#pragma unroll
        for (int ph = 0; ph < 8; ++ph) {
            int i = ph * 256 + tid;
            int r  = i >> 3;             // 0..255
            int c4 = i & 7;              // 0..7
            int grow = min(row0 + r, N_NODES - 1);
            float4 v = x4[(size_t)grow * 64 + kb * 8 + c4];
            xs4[r * 8 + (c4 ^ ((r >> 2) & 7))] = v;
        }
        __syncthreads();

#pragma unroll
        for (int k4 = 0; k4 < 8; ++k4) {
            float4 xv[4];
#pragma unroll
            for (int r = 0; r < 4; ++r)
                xv[r] = xs4[(rg * 4 + r) * 8 + (k4 ^ (rg & 7))];
#pragma unroll
            for (int j = 0; j < 10; ++j) {
                float4 w = wt4[(c0 + j) * 65 + kb * 8 + k4];
#pragma unroll
                for (int r = 0; r < 4; ++r)
                    acc[r][j] = fmaf(xv[r].x, w.x,
                                fmaf(xv[r].y, w.y,
                                fmaf(xv[r].z, w.z,
                                fmaf(xv[r].w, w.w, acc[r][j]))));
            }
        }
    }

#pragma unroll
    for (int r = 0; r < 4; ++r) {
        int row = row0 + rg * 4 + r;
        if (row < N_NODES) {
            size_t ob = (size_t)row * N_CLASS + c0;
#pragma unroll
            for (int j = 0; j < 10; ++j) T[ob + j] = acc[r][j];
        }
    }
}

// ---------------------------------------------------------------------------
// hist: cnt[dst]++ only (CSR fallback path)
// ---------------------------------------------------------------------------
__global__ __launch_bounds__(256) void hist_kernel(
    const int* __restrict__ edst, int* __restrict__ cnt)
{
    int e = blockIdx.x * 256 + threadIdx.x;
    if (e >= N_EDGES) return;
    atomicAdd(&cnt[edst[e]], 1);
}

// ---------------------------------------------------------------------------
// 3-phase parallel exclusive scan of cnt -> row_ptr (CSR fallback path)
// ---------------------------------------------------------------------------
__global__ __launch_bounds__(256) void scan_partial_kernel(
    const int* __restrict__ cnt, int* __restrict__ bsum)
{
    __shared__ int red[256];
    int t = threadIdx.x;
    int idx = blockIdx.x * SCAN_CHUNK + t;
    int v = (idx < N_NODES) ? cnt[idx] : 0;
    red[t] = v;
    __syncthreads();
#pragma unroll
    for (int off = 128; off > 0; off >>= 1) {
        if (t < off) red[t] += red[t + off];
        __syncthreads();
    }
    if (t == 0) bsum[blockIdx.x] = red[0];
}

__global__ __launch_bounds__(512) void scan_block_kernel(
    const int* __restrict__ bsum, int* __restrict__ boff)
{
    __shared__ int s[512];
    int t = threadIdx.x;
    int v = (t < SCAN_NB) ? bsum[t] : 0;
    s[t] = v;
    __syncthreads();
#pragma unroll
    for (int off = 1; off < 512; off <<= 1) {
        int u = (t >= off) ? s[t - off] : 0;
        __syncthreads();
        s[t] += u;
        __syncthreads();
    }
    if (t < SCAN_NB) boff[t] = s[t] - v;   // exclusive
}

__global__ __launch_bounds__(256) void scan_final_kernel(
    const int* __restrict__ cnt, const int* __restrict__ boff,
    int* __restrict__ row_ptr)
{
    __shared__ int s[256];
    int t = threadIdx.x;
    int idx = blockIdx.x * SCAN_CHUNK + t;
    int v = (idx < N_NODES) ? cnt[idx] : 0;
    s[t] = v;
    __syncthreads();
#pragma unroll
    for (int off = 1; off < 256; off <<= 1) {
        int u = (t >= off) ? s[t - off] : 0;
        __syncthreads();
        s[t] += u;
        __syncthreads();
    }
    if (idx < N_NODES) row_ptr[idx] = boff[blockIdx.x] + s[t] - v;
}

// ---------------------------------------------------------------------------
// fill (CSR fallback): pos = row_ptr[d]++; afterwards row_ptr[d] = end of row d
// ---------------------------------------------------------------------------
__global__ __launch_bounds__(256) void fill_kernel(
    const int* __restrict__ esrc, const int* __restrict__ edst,
    const float* __restrict__ ew, int* __restrict__ row_ptr,
    int2* __restrict__ edges_s)
{
    int e = blockIdx.x * 256 + threadIdx.x;
    if (e >= N_EDGES) return;
    int d = edst[e];
    int pos = atomicAdd(&row_ptr[d], 1);
    edges_s[pos] = make_int2(esrc[e], __float_as_int(ew[e]));
}

// ---------------------------------------------------------------------------
// fill (slots): one pass, no hist/scan. slot = cnt[d]++; bucket at d*SLOT_MAX.
// ---------------------------------------------------------------------------
__global__ __launch_bounds__(256) void fill_slots_kernel(
    const int* __restrict__ esrc, const int* __restrict__ edst,
    const float* __restrict__ ew, int* __restrict__ cnt,
    int2* __restrict__ slots)
{
    int e = blockIdx.x * 256 + threadIdx.x;
    if (e >= N_EDGES) return;
    int d = edst[e];
    int slot = atomicAdd(&cnt[d], 1);
    if (slot < SLOT_MAX)
        slots[(size_t)d * SLOT_MAX + slot] = make_int2(esrc[e], __float_as_int(ew[e]));
}

// ---------------------------------------------------------------------------
// agg: Tout[d,:] = sum_e w_e * Tin[src_e,:]. 10 lanes x float4 per node,
// 25 nodes / 256-block. Also writes deg_w[d] = sum_e w_e (sub==0 lane).
// ---------------------------------------------------------------------------
template<bool SLOTS>
__global__ __launch_bounds__(256) void agg_kernel(
    const int2* __restrict__ edges_s, const int* __restrict__ meta,
    const float* __restrict__ Tin, float* __restrict__ Tout,
    float* __restrict__ deg_w)
{
    const int t = threadIdx.x;
    if (t >= 250) return;
    const int node = blockIdx.x * 25 + t / 10;
    if (node >= N_NODES) return;
    const int sub = t % 10;

    int beg, end;
    if (SLOTS) {
        beg = node * SLOT_MAX;
        int c = meta[node];
        end = beg + (c > SLOT_MAX ? SLOT_MAX : c);
    } else {
        beg = node ? meta[node - 1] : 0;
        end = meta[node];
    }

    const float4* Tin4 = (const float4*)Tin;
    float4 acc = make_float4(0.f, 0.f, 0.f, 0.f);
    float wsum = 0.f;

    int e = beg;
    for (; e + 1 < end; e += 2) {
        int2 r0 = edges_s[e];
        int2 r1 = edges_s[e + 1];
        float w0 = __int_as_float(r0.y);
        float w1 = __int_as_float(r1.y);
        float4 v0 = Tin4[(size_t)r0.x * 10 + sub];
        float4 v1 = Tin4[(size_t)r1.x * 10 + sub];
        acc.x = fmaf(w0, v0.x, acc.x); acc.y = fmaf(w0, v0.y, acc.y);
        acc.z = fmaf(w0, v0.z, acc.z); acc.w = fmaf(w0, v0.w, acc.w);
        acc.x = fmaf(w1, v1.x, acc.x); acc.y = fmaf(w1, v1.y, acc.y);
        acc.z = fmaf(w1, v1.z, acc.z); acc.w = fmaf(w1, v1.w, acc.w);
        wsum += w0 + w1;
    }
    if (e < end) {
        int2 r0 = edges_s[e];
        float w0 = __int_as_float(r0.y);
        float4 v0 = Tin4[(size_t)r0.x * 10 + sub];
        acc.x = fmaf(w0, v0.x, acc.x); acc.y = fmaf(w0, v0.y, acc.y);
        acc.z = fmaf(w0, v0.z, acc.z); acc.w = fmaf(w0, v0.w, acc.w);
        wsum += w0;
    }

    ((float4*)Tout)[(size_t)node * 10 + sub] = acc;
    if (sub == 0) deg_w[node] = wsum;   // same A both layers -> idempotent
}

// ---------------------------------------------------------------------------
// log_softmax over rows of (Y2 + deg_w*c1 + b2). One wave per row.
// ---------------------------------------------------------------------------
__global__ __launch_bounds__(256) void softmax_kernel(
    const float* __restrict__ Y2, const float* __restrict__ deg_w,
    const float* __restrict__ c1, const float* __restrict__ b2,
    float* __restrict__ out)
{
    int row = blockIdx.x * 4 + (threadIdx.x >> 6);
    int lane = threadIdx.x & 63;
    if (row >= N_NODES) return;

    float z = -INFINITY;
    if (lane < N_CLASS)
        z = Y2[(size_t)row * N_CLASS + lane] + deg_w[row] * c1[lane] + b2[lane];

    float m = z;
#pragma unroll
    for (int o = 32; o > 0; o >>= 1) m = fmaxf(m, __shfl_xor(m, o, 64));

    float ex = (lane < N_CLASS) ? expf(z - m) : 0.f;
    float ssum = ex;
#pragma unroll
    for (int o = 32; o > 0; o >>= 1) ssum += __shfl_xor(ssum, o, 64);

    if (lane < N_CLASS) out[(size_t)row * N_CLASS + lane] = z - m - logf(ssum);
}

// ---------------------------------------------------------------------------
extern "C" void kernel_launch(void* const* d_in, const int* in_sizes, int n_in,
                              void* d_out, int out_size, void* d_ws, size_t ws_size,
                              hipStream_t stream)
{
    const float* x    = (const float*)d_in[0];
    const int*   esrc = (const int*)  d_in[1];
    const int*   edst = (const int*)  d_in[2];
    const float* ew   = (const float*)d_in[3];
    const float* W1   = (const float*)d_in[4];
    const float* b1   = (const float*)d_in[5];
    const float* W2   = (const float*)d_in[6];
    const float* b2   = (const float*)d_in[7];
    float* out = (float*)d_out;

    char* ws = (char*)d_ws;
    const size_t SLOTS_BYTES = (size_t)N_NODES * SLOT_MAX * 8;     // 38.4 MB
    const size_t NEED_SLOTS  = SLOTS_BYTES + 32000000 + 1000000;   // ~71.4 MB
    const bool use_slots = (ws_size >= NEED_SLOTS);

    const int GEMM_NB = (N_NODES + 255) / 256;   // 391

    if (use_slots) {
        int2*  slots = (int2*) (ws);
        float* T     = (float*)(ws + SLOTS_BYTES);                  // 16 MB
        float* Y1    = (float*)(ws + SLOTS_BYTES + 16000000);       // 16 MB
        int*   cnt   = (int*)  (ws + SLOTS_BYTES + 32000000);       // 400 KB
        float* deg_w = (float*)(ws + SLOTS_BYTES + 32400000);       // 400 KB
        float* W12t  = (float*)(ws + SLOTS_BYTES + 32800000);       // 40 KB
        float* c1    = (float*)(ws + SLOTS_BYTES + 32841984);
        float* Y2    = T;

        hipMemsetAsync(cnt, 0, 400000, stream);
        prep_kernel<<<(D_IN * N_CLASS + 255) / 256, 256, 0, stream>>>(W1, W2, b1, W12t, c1);
        gemm_t_kernel<<<GEMM_NB, 256, 0, stream>>>(x, W12t, T);
        fill_slots_kernel<<<(N_EDGES + 255) / 256, 256, 0, stream>>>(esrc, edst, ew, cnt, slots);
        agg_kernel<true><<<(N_NODES + 24) / 25, 256, 0, stream>>>(slots, cnt, T, Y1, deg_w);
        agg_kernel<true><<<(N_NODES + 24) / 25, 256, 0, stream>>>(slots, cnt, Y1, Y2, deg_w);
        softmax_kernel<<<(N_NODES + 3) / 4, 256, 0, stream>>>(Y2, deg_w, c1, b2, out);
    } else {
        float* T       = (float*)(ws);                         // 16 MB (also Y2)
        float* Y1      = (float*)(ws + 16000000);              // 16 MB
        int2*  edges_s = (int2*) (ws + 32000000);              // 12.8 MB
        int*   row_ptr = (int*)  (ws + 44800000);              // 400 KB
        int*   cnt     = (int*)  (ws + 45200016);              // 400 KB
        float* deg_w   = (float*)(ws + 45600016);              // 400 KB
        float* W12t    = (float*)(ws + 46000016);              // 40 KB
        float* c1      = (float*)(ws + 46040976);
        int*   bsum    = (int*)  (ws + 46041200);
        int*   boff    = (int*)  (ws + 46042800);
        float* Y2      = T;

        hipMemsetAsync(cnt, 0, 400000, stream);
        prep_kernel<<<(D_IN * N_CLASS + 255) / 256, 256, 0, stream>>>(W1, W2, b1, W12t, c1);
        gemm_t_kernel<<<GEMM_NB, 256, 0, stream>>>(x, W12t, T);
        hist_kernel<<<(N_EDGES + 255) / 256, 256, 0, stream>>>(edst, cnt);
        scan_partial_kernel<<<SCAN_NB, 256, 0, stream>>>(cnt, bsum);
        scan_block_kernel<<<1, 512, 0, stream>>>(bsum, boff);
        scan_final_kernel<<<SCAN_NB, 256, 0, stream>>>(cnt, boff, row_ptr);
        fill_kernel<<<(N_EDGES + 255) / 256, 256, 0, stream>>>(esrc, edst, ew, row_ptr, edges_s);
        agg_kernel<false><<<(N_NODES + 24) / 25, 256, 0, stream>>>(edges_s, row_ptr, T, Y1, deg_w);
        agg_kernel<false><<<(N_NODES + 24) / 25, 256, 0, stream>>>(edges_s, row_ptr, Y1, Y2, deg_w);
        softmax_kernel<<<(N_NODES + 3) / 4, 256, 0, stream>>>(Y2, deg_w, c1, b2, out);
    }
}

// Round 7
// 378.531 us; speedup vs baseline: 2.2389x; 1.2013x over previous
//
#include <hip/hip_runtime.h>
#include <hip/hip_bf16.h>
#include <math.h>

#define N_NODES 100000
#define N_EDGES 1600000
#define D_IN    256
#define D_HID   64
#define N_CLASS 40

#define SCAN_CHUNK 256
#define SCAN_NB    ((N_NODES + SCAN_CHUNK - 1) / SCAN_CHUNK)   // 391
#define SLOT_MAX   48     // Binomial(1.6M,1e-5): mean 16, P(deg>48) ~ 1e-10
#define GEMM_NB    ((N_NODES + 255) / 256)                     // 391
#define FILL_NB    ((N_EDGES + 255) / 256)                     // 6250

// ---------------------------------------------------------------------------
// prep: W12t[c][k] = sum_j W1[k][j]*W2[j][c]  (transposed 40x256),
//       c1[c] = sum_j b1[j]*W2[j][c]
// ---------------------------------------------------------------------------
__global__ __launch_bounds__(256) void prep_kernel(
    const float* __restrict__ W1, const float* __restrict__ W2,
    const float* __restrict__ b1, float* __restrict__ W12t, float* __restrict__ c1)
{
    int idx = blockIdx.x * 256 + threadIdx.x;
    if (idx < D_IN * N_CLASS) {
        int k = idx / N_CLASS;
        int c = idx - k * N_CLASS;
        float s = 0.f;
#pragma unroll
        for (int j = 0; j < D_HID; ++j)
            s = fmaf(W1[k * D_HID + j], W2[j * N_CLASS + c], s);
        W12t[c * D_IN + k] = s;
    }
    if (blockIdx.x == 0 && threadIdx.x < N_CLASS) {
        int c = threadIdx.x;
        float s = 0.f;
#pragma unroll
        for (int j = 0; j < D_HID; ++j)
            s = fmaf(b1[j], W2[j * N_CLASS + c], s);
        c1[c] = s;
    }
}

// ---------------------------------------------------------------------------
// gemm body (v3, verified R6): 256 rows x 40 cols per block, both operands
// in LDS, XOR-swizzled X tile, thread = 4 rows x 10 cols. VALU-bound.
// ---------------------------------------------------------------------------
__device__ __forceinline__ void gemm_body(
    int gblk, int tid,
    const float* __restrict__ x, const float* __restrict__ W12t,
    float* __restrict__ T, float* xs, float* wt)
{
    const int row0 = gblk * 256;

    for (int i = tid; i < N_CLASS * D_IN; i += 256) {
        int c = i >> 8;
        int k = i & 255;
        wt[c * 260 + k] = W12t[i];
    }

    const int rg = tid >> 2;       // 0..63  (4 rows each)
    const int cg = tid & 3;        // 0..3   (10 cols each)
    const int c0 = cg * 10;

    float acc[4][10];
#pragma unroll
    for (int r = 0; r < 4; ++r)
#pragma unroll
        for (int j = 0; j < 10; ++j) acc[r][j] = 0.f;

    const float4* x4 = (const float4*)x;
    float4* xs4 = (float4*)xs;
    const float4* wt4 = (const float4*)wt;

    for (int kb = 0; kb < 8; ++kb) {
        __syncthreads();
#pragma unroll
        for (int ph = 0; ph < 8; ++ph) {
            int i = ph * 256 + tid;
            int r  = i >> 3;
            int c4 = i & 7;
            int grow = min(row0 + r, N_NODES - 1);
            float4 v = x4[(size_t)grow * 64 + kb * 8 + c4];
            xs4[r * 8 + (c4 ^ ((r >> 2) & 7))] = v;
        }
        __syncthreads();

#pragma unroll
        for (int k4 = 0; k4 < 8; ++k4) {
            float4 xv[4];
#pragma unroll
            for (int r = 0; r < 4; ++r)
                xv[r] = xs4[(rg * 4 + r) * 8 + (k4 ^ (rg & 7))];
#pragma unroll
            for (int j = 0; j < 10; ++j) {
                float4 w = wt4[(c0 + j) * 65 + kb * 8 + k4];
#pragma unroll
                for (int r = 0; r < 4; ++r)
                    acc[r][j] = fmaf(xv[r].x, w.x,
                                fmaf(xv[r].y, w.y,
                                fmaf(xv[r].z, w.z,
                                fmaf(xv[r].w, w.w, acc[r][j]))));
            }
        }
    }

#pragma unroll
    for (int r = 0; r < 4; ++r) {
        int row = row0 + rg * 4 + r;
        if (row < N_NODES) {
            size_t ob = (size_t)row * N_CLASS + c0;
#pragma unroll
            for (int j = 0; j < 10; ++j) T[ob + j] = acc[r][j];
        }
    }
}

// ---------------------------------------------------------------------------
// fused gemm + fill_slots: blocks [0,GEMM_NB) do the dense transform,
// blocks [GEMM_NB, GEMM_NB+FILL_NB) do slot-binning. Independent work —
// fused so the VALU-heavy gemm overlaps the atomic/store-heavy fill
// (stream is serial and hipEvent* is banned, so fusion is the only overlap).
// ---------------------------------------------------------------------------
__global__ __launch_bounds__(256) void gemm_fill_kernel(
    const float* __restrict__ x, const float* __restrict__ W12t,
    float* __restrict__ T,
    const int* __restrict__ esrc, const int* __restrict__ edst,
    const float* __restrict__ ew, int* __restrict__ cnt,
    int2* __restrict__ slots)
{
    __shared__ float xs[256 * 32];      // 32 KB
    __shared__ float wt[N_CLASS * 260]; // 41.6 KB  (74.4 KB -> 2 blocks/CU)
    const int tid = threadIdx.x;

    if (blockIdx.x < GEMM_NB) {
        gemm_body(blockIdx.x, tid, x, W12t, T, xs, wt);
    } else {
        int e = (blockIdx.x - GEMM_NB) * 256 + tid;
        if (e < N_EDGES) {
            int d = edst[e];
            int slot = atomicAdd(&cnt[d], 1);
            if (slot < SLOT_MAX)
                slots[(size_t)d * SLOT_MAX + slot] =
                    make_int2(esrc[e], __float_as_int(ew[e]));
        }
    }
}

// standalone gemm (CSR fallback path)
__global__ __launch_bounds__(256) void gemm_t_kernel(
    const float* __restrict__ x, const float* __restrict__ W12t,
    float* __restrict__ T)
{
    __shared__ float xs[256 * 32];
    __shared__ float wt[N_CLASS * 260];
    gemm_body(blockIdx.x, threadIdx.x, x, W12t, T, xs, wt);
}

// ---------------------------------------------------------------------------
// CSR fallback: hist + 3-phase scan + fill
// ---------------------------------------------------------------------------
__global__ __launch_bounds__(256) void hist_kernel(
    const int* __restrict__ edst, int* __restrict__ cnt)
{
    int e = blockIdx.x * 256 + threadIdx.x;
    if (e >= N_EDGES) return;
    atomicAdd(&cnt[edst[e]], 1);
}

__global__ __launch_bounds__(256) void scan_partial_kernel(
    const int* __restrict__ cnt, int* __restrict__ bsum)
{
    __shared__ int red[256];
    int t = threadIdx.x;
    int idx = blockIdx.x * SCAN_CHUNK + t;
    int v = (idx < N_NODES) ? cnt[idx] : 0;
    red[t] = v;
    __syncthreads();
#pragma unroll
    for (int off = 128; off > 0; off >>= 1) {
        if (t < off) red[t] += red[t + off];
        __syncthreads();
    }
    if (t == 0) bsum[blockIdx.x] = red[0];
}

__global__ __launch_bounds__(512) void scan_block_kernel(
    const int* __restrict__ bsum, int* __restrict__ boff)
{
    __shared__ int s[512];
    int t = threadIdx.x;
    int v = (t < SCAN_NB) ? bsum[t] : 0;
    s[t] = v;
    __syncthreads();
#pragma unroll
    for (int off = 1; off < 512; off <<= 1) {
        int u = (t >= off) ? s[t - off] : 0;
        __syncthreads();
        s[t] += u;
        __syncthreads();
    }
    if (t < SCAN_NB) boff[t] = s[t] - v;
}

__global__ __launch_bounds__(256) void scan_final_kernel(
    const int* __restrict__ cnt, const int* __restrict__ boff,
    int* __restrict__ row_ptr)
{
    __shared__ int s[256];
    int t = threadIdx.x;
    int idx = blockIdx.x * SCAN_CHUNK + t;
    int v = (idx < N_NODES) ? cnt[idx] : 0;
    s[t] = v;
    __syncthreads();
#pragma unroll
    for (int off = 1; off < 256; off <<= 1) {
        int u = (t >= off) ? s[t - off] : 0;
        __syncthreads();
        s[t] += u;
        __syncthreads();
    }
    if (idx < N_NODES) row_ptr[idx] = boff[blockIdx.x] + s[t] - v;
}

__global__ __launch_bounds__(256) void fill_kernel(
    const int* __restrict__ esrc, const int* __restrict__ edst,
    const float* __restrict__ ew, int* __restrict__ row_ptr,
    int2* __restrict__ edges_s)
{
    int e = blockIdx.x * 256 + threadIdx.x;
    if (e >= N_EDGES) return;
    int d = edst[e];
    int pos = atomicAdd(&row_ptr[d], 1);
    edges_s[pos] = make_int2(esrc[e], __float_as_int(ew[e]));
}

// ---------------------------------------------------------------------------
// agg: Tout[d,:] = sum_e w_e * Tin[src_e,:].  10 lanes x float4 per node,
// 25 nodes / 256-block. 4-wide edge unroll: 4 record loads then 4 gathers
// in flight per iteration (2x the MLP of the R6 2-wide loop).
// SMAX: fused bias + deg_w*c1 + log_softmax epilogue (LDS reduce over the
// node's 10 threads); no separate softmax pass, deg_w never hits global.
// ---------------------------------------------------------------------------
template<bool SLOTS, bool SMAX>
__global__ __launch_bounds__(256) void agg_kernel(
    const int2* __restrict__ edges_s, const int* __restrict__ meta,
    const float* __restrict__ Tin, float* __restrict__ Tout,
    const float* __restrict__ c1, const float* __restrict__ b2)
{
    __shared__ float red[25][11];
    __shared__ float wsh[25];
    const int t = threadIdx.x;
    const int nl  = t / 10;                 // 0..25 (idle if >=25)
    const int sub = t % 10;
    const int node = blockIdx.x * 25 + nl;
    const bool active = (t < 250) && (node < N_NODES);

    int beg = 0, end = 0;
    if (active) {
        if (SLOTS) {
            beg = node * SLOT_MAX;
            int c = meta[node];
            end = beg + (c > SLOT_MAX ? SLOT_MAX : c);
        } else {
            beg = node ? meta[node - 1] : 0;
            end = meta[node];
        }
    }

    const float4* Tin4 = (const float4*)Tin;
    float4 acc = make_float4(0.f, 0.f, 0.f, 0.f);
    float wsum = 0.f;

    int e = beg;
    for (; e + 3 < end; e += 4) {
        int2 a0 = edges_s[e];
        int2 a1 = edges_s[e + 1];
        int2 a2 = edges_s[e + 2];
        int2 a3 = edges_s[e + 3];
        float4 v0 = Tin4[a0.x * 10 + sub];
        float4 v1 = Tin4[a1.x * 10 + sub];
        float4 v2 = Tin4[a2.x * 10 + sub];
        float4 v3 = Tin4[a3.x * 10 + sub];
        float w0 = __int_as_float(a0.y), w1 = __int_as_float(a1.y);
        float w2 = __int_as_float(a2.y), w3 = __int_as_float(a3.y);
        acc.x = fmaf(w0, v0.x, acc.x); acc.y = fmaf(w0, v0.y, acc.y);
        acc.z = fmaf(w0, v0.z, acc.z); acc.w = fmaf(w0, v0.w, acc.w);
        acc.x = fmaf(w1, v1.x, acc.x); acc.y = fmaf(w1, v1.y, acc.y);
        acc.z = fmaf(w1, v1.z, acc.z); acc.w = fmaf(w1, v1.w, acc.w);
        acc.x = fmaf(w2, v2.x, acc.x); acc.y = fmaf(w2, v2.y, acc.y);
        acc.z = fmaf(w2, v2.z, acc.z); acc.w = fmaf(w2, v2.w, acc.w);
        acc.x = fmaf(w3, v3.x, acc.x); acc.y = fmaf(w3, v3.y, acc.y);
        acc.z = fmaf(w3, v3.z, acc.z); acc.w = fmaf(w3, v3.w, acc.w);
        if (SMAX) wsum += (w0 + w1) + (w2 + w3);
    }
    for (; e < end; ++e) {
        int2 a0 = edges_s[e];
        float w0 = __int_as_float(a0.y);
        float4 v0 = Tin4[a0.x * 10 + sub];
        acc.x = fmaf(w0, v0.x, acc.x); acc.y = fmaf(w0, v0.y, acc.y);
        acc.z = fmaf(w0, v0.z, acc.z); acc.w = fmaf(w0, v0.w, acc.w);
        if (SMAX) wsum += w0;
    }

    if (!SMAX) {
        if (active) ((float4*)Tout)[(size_t)node * 10 + sub] = acc;
        return;
    }

    // ---- fused bias + log_softmax epilogue (all 256 threads hit syncs) ----
    if (active && sub == 0) wsh[nl] = wsum;
    __syncthreads();
    float dw = active ? wsh[nl] : 0.f;

    float4 cv = ((const float4*)c1)[sub];
    float4 bv = ((const float4*)b2)[sub];
    float4 z;
    z.x = fmaf(dw, cv.x, acc.x + bv.x);
    z.y = fmaf(dw, cv.y, acc.y + bv.y);
    z.z = fmaf(dw, cv.z, acc.z + bv.z);
    z.w = fmaf(dw, cv.w, acc.w + bv.w);

    float m4 = fmaxf(fmaxf(z.x, z.y), fmaxf(z.z, z.w));
    if (active) red[nl][sub] = m4;
    __syncthreads();
    float m = -INFINITY;
    if (active)
#pragma unroll
        for (int j = 0; j < 10; ++j) m = fmaxf(m, red[nl][j]);
    __syncthreads();

    float s4 = expf(z.x - m) + expf(z.y - m) + expf(z.z - m) + expf(z.w - m);
    if (active) red[nl][sub] = s4;
    __syncthreads();
    if (active) {
        float s = 0.f;
#pragma unroll
        for (int j = 0; j < 10; ++j) s += red[nl][j];
        float ls = m + logf(s);
        float4 o;
        o.x = z.x - ls; o.y = z.y - ls; o.z = z.z - ls; o.w = z.w - ls;
        ((float4*)Tout)[(size_t)node * 10 + sub] = o;
    }
}

// ---------------------------------------------------------------------------
extern "C" void kernel_launch(void* const* d_in, const int* in_sizes, int n_in,
                              void* d_out, int out_size, void* d_ws, size_t ws_size,
                              hipStream_t stream)
{
    const float* x    = (const float*)d_in[0];
    const int*   esrc = (const int*)  d_in[1];
    const int*   edst = (const int*)  d_in[2];
    const float* ew   = (const float*)d_in[3];
    const float* W1   = (const float*)d_in[4];
    const float* b1   = (const float*)d_in[5];
    const float* W2   = (const float*)d_in[6];
    const float* b2   = (const float*)d_in[7];
    float* out = (float*)d_out;

    char* ws = (char*)d_ws;
    const size_t SLOTS_BYTES = (size_t)N_NODES * SLOT_MAX * 8;     // 38.4 MB
    const size_t NEED_SLOTS  = SLOTS_BYTES + 32000000 + 1000000;   // ~71.4 MB
    const bool use_slots = (ws_size >= NEED_SLOTS);

    if (use_slots) {
        int2*  slots = (int2*) (ws);
        float* T     = (float*)(ws + SLOTS_BYTES);                  // 16 MB
        float* Y1    = (float*)(ws + SLOTS_BYTES + 16000000);       // 16 MB
        int*   cnt   = (int*)  (ws + SLOTS_BYTES + 32000000);       // 400 KB
        float* W12t  = (float*)(ws + SLOTS_BYTES + 32400000);       // 40 KB
        float* c1    = (float*)(ws + SLOTS_BYTES + 32441984);

        hipMemsetAsync(cnt, 0, 400000, stream);
        prep_kernel<<<(D_IN * N_CLASS + 255) / 256, 256, 0, stream>>>(W1, W2, b1, W12t, c1);
        gemm_fill_kernel<<<GEMM_NB + FILL_NB, 256, 0, stream>>>(
            x, W12t, T, esrc, edst, ew, cnt, slots);
        agg_kernel<true, false><<<(N_NODES + 24) / 25, 256, 0, stream>>>(
            slots, cnt, T, Y1, nullptr, nullptr);
        agg_kernel<true, true><<<(N_NODES + 24) / 25, 256, 0, stream>>>(
            slots, cnt, Y1, out, c1, b2);
    } else {
        float* T       = (float*)(ws);                         // 16 MB
        float* Y1      = (float*)(ws + 16000000);              // 16 MB
        int2*  edges_s = (int2*) (ws + 32000000);              // 12.8 MB
        int*   row_ptr = (int*)  (ws + 44800000);              // 400 KB
        int*   cnt     = (int*)  (ws + 45200016);              // 400 KB
        float* W12t    = (float*)(ws + 45600016);              // 40 KB
        float* c1      = (float*)(ws + 45640976);
        int*   bsum    = (int*)  (ws + 45641200);
        int*   boff    = (int*)  (ws + 45642800);

        hipMemsetAsync(cnt, 0, 400000, stream);
        prep_kernel<<<(D_IN * N_CLASS + 255) / 256, 256, 0, stream>>>(W1, W2, b1, W12t, c1);
        gemm_t_kernel<<<GEMM_NB, 256, 0, stream>>>(x, W12t, T);
        hist_kernel<<<FILL_NB, 256, 0, stream>>>(edst, cnt);
        scan_partial_kernel<<<SCAN_NB, 256, 0, stream>>>(cnt, bsum);
        scan_block_kernel<<<1, 512, 0, stream>>>(bsum, boff);
        scan_final_kernel<<<SCAN_NB, 256, 0, stream>>>(cnt, boff, row_ptr);
        fill_kernel<<<FILL_NB, 256, 0, stream>>>(esrc, edst, ew, row_ptr, edges_s);
        agg_kernel<false, false><<<(N_NODES + 24) / 25, 256, 0, stream>>>(
            edges_s, row_ptr, T, Y1, nullptr, nullptr);
        agg_kernel<false, true><<<(N_NODES + 24) / 25, 256, 0, stream>>>(
            edges_s, row_ptr, Y1, out, c1, b2);
    }
}